// Round 1
// baseline (109.785 us; speedup 1.0000x reference)
//
#include <hip/hip_runtime.h>

// out_real = x_real * exp(betas_real) broadcast over (b,c); same for imag.
// Memory-bound elementwise: float4 loads/stores, grid-stride, inline __expf.
// betas (256 KB each) are L2-resident; hw period 65536 is divisible by 4 so
// float4 blocks never straddle the broadcast period -> betas indexed as float4.

__global__ __launch_bounds__(256) void diag_exp_scale(
    const float4* __restrict__ xr4,
    const float4* __restrict__ xi4,
    const float4* __restrict__ br4,
    const float4* __restrict__ bi4,
    float4* __restrict__ outr4,
    float4* __restrict__ outi4,
    int n4)  // float4 count per tensor
{
    const int HW4 = 16384;  // (256*256)/4
    int stride = gridDim.x * blockDim.x;
    for (int i = blockIdx.x * blockDim.x + threadIdx.x; i < n4; i += stride) {
        int m = i & (HW4 - 1);
        float4 sr = br4[m];
        float4 si = bi4[m];
        float4 vr = xr4[i];
        float4 vi = xi4[i];
        float4 r, im;
        r.x  = vr.x * __expf(sr.x);
        r.y  = vr.y * __expf(sr.y);
        r.z  = vr.z * __expf(sr.z);
        r.w  = vr.w * __expf(sr.w);
        im.x = vi.x * __expf(si.x);
        im.y = vi.y * __expf(si.y);
        im.z = vi.z * __expf(si.z);
        im.w = vi.w * __expf(si.w);
        outr4[i] = r;
        outi4[i] = im;
    }
}

extern "C" void kernel_launch(void* const* d_in, const int* in_sizes, int n_in,
                              void* d_out, int out_size, void* d_ws, size_t ws_size,
                              hipStream_t stream) {
    const float* xr = (const float*)d_in[0];   // x_real  (b*c*h*w)
    const float* xi = (const float*)d_in[1];   // x_imag
    const float* br = (const float*)d_in[2];   // betas_real (h*w)
    const float* bi = (const float*)d_in[3];   // betas_imag

    float* out = (float*)d_out;
    int n  = in_sizes[0];   // 33,554,432
    int n4 = n >> 2;        // 8,388,608 float4 per tensor

    float* outr = out;      // out_real first, then out_imag (tuple concat)
    float* outi = out + n;

    const int threads = 256;
    const int blocks  = 2048;  // 256 CU x 8 blocks, grid-stride covers the rest
    diag_exp_scale<<<blocks, threads, 0, stream>>>(
        (const float4*)xr, (const float4*)xi,
        (const float4*)br, (const float4*)bi,
        (float4*)outr, (float4*)outi, n4);
}

// Round 2
// 97.703 us; speedup vs baseline: 1.1237x; 1.1237x over previous
//
#include <hip/hip_runtime.h>

// out = x * exp(betas), betas broadcast over the 512 (b*c) planes.
// Key restructure vs R0: thread t owns ONE hw-column (m = t & (HW4-1)) and
// loops over its group's planes, so the betas load + 8 expf run ONCE per
// thread instead of once per iteration. Hot loop = pure load/mul/store,
// independent iterations, nontemporal (streaming) hints on x and out.

typedef float f32x4 __attribute__((ext_vector_type(4)));

__global__ __launch_bounds__(256) void diag_exp_scale(
    const f32x4* __restrict__ xr4,
    const f32x4* __restrict__ xi4,
    const f32x4* __restrict__ br4,
    const f32x4* __restrict__ bi4,
    f32x4* __restrict__ outr4,
    f32x4* __restrict__ outi4,
    int hw4,              // (h*w)/4, power of two (16384)
    int planes_per_group, // planes each thread-group covers (16)
    int nplanes)          // b*c (512)
{
    int t = blockIdx.x * blockDim.x + threadIdx.x;
    int m = t & (hw4 - 1);        // hw column owned by this thread
    int g = t / hw4;              // plane group

    // Loop-invariant scale: one L2 load + 4 expf per tensor, hoisted.
    f32x4 sr = br4[m];
    f32x4 si = bi4[m];
    sr.x = __expf(sr.x); sr.y = __expf(sr.y);
    sr.z = __expf(sr.z); sr.w = __expf(sr.w);
    si.x = __expf(si.x); si.y = __expf(si.y);
    si.z = __expf(si.z); si.w = __expf(si.w);

    int p0 = g * planes_per_group;
    int p1 = p0 + planes_per_group;
    if (p1 > nplanes) p1 = nplanes;

    #pragma unroll 4
    for (int p = p0; p < p1; ++p) {
        int idx = p * hw4 + m;    // max 512*16384 = 8.4M, fits int
        f32x4 vr = __builtin_nontemporal_load(&xr4[idx]);
        f32x4 vi = __builtin_nontemporal_load(&xi4[idx]);
        f32x4 r  = vr * sr;
        f32x4 im = vi * si;
        __builtin_nontemporal_store(r,  &outr4[idx]);
        __builtin_nontemporal_store(im, &outi4[idx]);
    }
}

extern "C" void kernel_launch(void* const* d_in, const int* in_sizes, int n_in,
                              void* d_out, int out_size, void* d_ws, size_t ws_size,
                              hipStream_t stream) {
    const float* xr = (const float*)d_in[0];   // x_real  (b*c*h*w)
    const float* xi = (const float*)d_in[1];   // x_imag
    const float* br = (const float*)d_in[2];   // betas_real (h*w)
    const float* bi = (const float*)d_in[3];   // betas_imag

    float* out = (float*)d_out;
    int n    = in_sizes[0];        // 33,554,432
    int hw   = in_sizes[2];        // 65,536
    int hw4  = hw >> 2;            // 16,384 (power of two)
    int nplanes = n / hw;          // 512

    float* outr = out;             // tuple concat: out_real then out_imag
    float* outi = out + n;

    const int threads = 256;
    const int ngroups = 32;                    // 32 groups x 16 planes = 512
    int planes_per_group = (nplanes + ngroups - 1) / ngroups;
    int total_threads = hw4 * ngroups;         // 524,288
    int blocks = total_threads / threads;      // 2048

    diag_exp_scale<<<blocks, threads, 0, stream>>>(
        (const f32x4*)xr, (const f32x4*)xi,
        (const f32x4*)br, (const f32x4*)bi,
        (f32x4*)outr, (f32x4*)outi,
        hw4, planes_per_group, nplanes);
}